// Round 5
// baseline (434.129 us; speedup 1.0000x reference)
//
#include <hip/hip_runtime.h>

#define B 16
#define S 2048
#define D 256

typedef float fx4 __attribute__((ext_vector_type(4)));

// Kernel 1: per-row projections. One 64-lane wave per (b,s) row.
// lane l handles d = 4l..4l+3 (64*4 = 256 = D exactly).
// Also packs sjm[row] = mask[row] ? sj : NaN  (tag for the j-masked select),
// eliminating the separate mask_j load in the fuse kernel.
__global__ __launch_bounds__(256) void rowdot_kernel(
    const float* __restrict__ x,     // [B*S, D]
    const float* __restrict__ W,     // [2*D]
    const float* __restrict__ bptr,  // [1]
    const int*   __restrict__ mask,  // [B*S]
    float* __restrict__ si,          // [B*S]  (stores si + b)
    float* __restrict__ sjm)         // [B*S]  (sj or NaN)
{
    const int wave = (blockIdx.x * blockDim.x + threadIdx.x) >> 6;
    const int lane = threadIdx.x & 63;
    if (wave >= B * S) return;

    const fx4 xv = *reinterpret_cast<const fx4*>(x + (size_t)wave * D + lane * 4);
    const fx4 wi = *reinterpret_cast<const fx4*>(W + lane * 4);
    const fx4 wj = *reinterpret_cast<const fx4*>(W + D + lane * 4);

    float a = xv.x * wi.x + xv.y * wi.y + xv.z * wi.z + xv.w * wi.w;
    float c = xv.x * wj.x + xv.y * wj.y + xv.z * wj.z + xv.w * wj.w;

    #pragma unroll
    for (int m = 32; m >= 1; m >>= 1) {
        a += __shfl_xor(a, m, 64);
        c += __shfl_xor(c, m, 64);
    }
    if (lane == 0) {
        si[wave]  = a + bptr[0];   // fold bias into si once
        sjm[wave] = mask[wave] ? c : __int_as_float(0x7FC00000);  // NaN tag
    }
}

__device__ __forceinline__ float blend_one(float sjv, float s_i, float adjv) {
    // sigmoid(arg) = 1 / (1 + 2^(-arg*log2(e))) via HW v_exp_f32 / v_rcp_f32
    const float arg = s_i + sjv;                 // NaN-propagating if masked
    const float e   = __builtin_amdgcn_exp2f(-1.44269504088896f * arg);
    const float sig = __builtin_amdgcn_rcpf(1.0f + e);
    const float v   = 0.6f * sig + 0.4f * adjv;
    return (sjv != sjv) ? 1e-9f : v;             // NaN tag -> mask fill
}

// Kernel 2: one block per (b,i) output row of 2048 elements.
// mask_i == 0  -> entire row is 1e-9: plain (fill-style) stores, no reads.
// mask_i == 1  -> 1 adj nt-load + 1 sjm load + 1 nt-store per float4.
__global__ __launch_bounds__(256) void fuse_kernel(
    const float* __restrict__ adj,   // [B, S, S]
    const int*   __restrict__ mask,  // [B, S]
    const float* __restrict__ si,    // [B*S] (si + b)
    const float* __restrict__ sjm,   // [B*S] (sj or NaN)
    float* __restrict__ out)         // [B, S, S]
{
    const int row  = blockIdx.x;                  // 0 .. B*S-1
    const long long base = (long long)row << 11;  // row * S
    const int t  = threadIdx.x;
    const int j0 = t << 2;                        // 0..1020 step 4

    const int mi = mask[row];                     // block-uniform
    if (mi == 0) {
        const fx4 fill = {1e-9f, 1e-9f, 1e-9f, 1e-9f};
        *reinterpret_cast<fx4*>(out + base + j0)        = fill;
        *reinterpret_cast<fx4*>(out + base + j0 + 1024) = fill;
        return;
    }

    const float s_i = si[row];                    // block-uniform scalar
    const int jb = (row >> 11) << 11;             // batch * S

    const fx4 a0 = __builtin_nontemporal_load(
        reinterpret_cast<const fx4*>(adj + base + j0));
    const fx4 a1 = __builtin_nontemporal_load(
        reinterpret_cast<const fx4*>(adj + base + j0 + 1024));
    const fx4 s0 = *reinterpret_cast<const fx4*>(sjm + jb + j0);
    const fx4 s1 = *reinterpret_cast<const fx4*>(sjm + jb + j0 + 1024);

    fx4 o0, o1;
    o0.x = blend_one(s0.x, s_i, a0.x);
    o0.y = blend_one(s0.y, s_i, a0.y);
    o0.z = blend_one(s0.z, s_i, a0.z);
    o0.w = blend_one(s0.w, s_i, a0.w);
    o1.x = blend_one(s1.x, s_i, a1.x);
    o1.y = blend_one(s1.y, s_i, a1.y);
    o1.z = blend_one(s1.z, s_i, a1.z);
    o1.w = blend_one(s1.w, s_i, a1.w);

    __builtin_nontemporal_store(o0, reinterpret_cast<fx4*>(out + base + j0));
    __builtin_nontemporal_store(o1, reinterpret_cast<fx4*>(out + base + j0 + 1024));
}

extern "C" void kernel_launch(void* const* d_in, const int* in_sizes, int n_in,
                              void* d_out, int out_size, void* d_ws, size_t ws_size,
                              hipStream_t stream) {
    const float* x    = (const float*)d_in[0];
    const float* adj  = (const float*)d_in[1];
    const int*   mask = (const int*)d_in[2];
    const float* W    = (const float*)d_in[3];
    const float* bptr = (const float*)d_in[4];
    float* out = (float*)d_out;

    float* si  = (float*)d_ws;          // B*S floats
    float* sjm = si + (size_t)B * S;    // B*S floats  (256 KB total << ws)

    // Kernel 1: one wave per row, 4 waves per block -> B*S/4 blocks.
    rowdot_kernel<<<(B * S) / 4, 256, 0, stream>>>(x, W, bptr, mask, si, sjm);

    // Kernel 2: one block per output row.
    fuse_kernel<<<B * S, 256, 0, stream>>>(adj, mask, si, sjm, out);
}